// Round 6
// baseline (127.982 us; speedup 1.0000x reference)
//
#include <hip/hip_runtime.h>

// ---------------------------------------------------------------------------
// RandomForest: 100 trees, depth 5, D=256, B=8192, C=64.
// r6: restore r1's fast GEMM shape (prep-split bf16 X, tg=8/N=128, acc[4][8])
// and remove in-loop staging entirely: W half-K (64KB) staged once, 3 barriers
// per block total (vs barrier+vmcnt drain per 2 kk-steps). Ladder logic:
// r3-r5 were ~410 TF-effective (step-0/1 class: in-loop split8 VALU ~2:1
// vs MFMA + N=64 halves MFMA density); r1 shape is step-2 class.
// MFMA order: 4 independent chains per pass (was 3 dependent back-to-back).
// Kept: rolled kk-loop, in-lane fp64 fixup, bf16 leaves, XCD swizzle.
// ---------------------------------------------------------------------------

typedef __bf16 bf16;
typedef __attribute__((ext_vector_type(8))) __bf16 bf16x8;
typedef __attribute__((ext_vector_type(4))) float f32x4;

#define NTREES 100
#define NB     8192
#define ND     256
#define NNODES 31
#define NLEAF  32
#define NCLS   64
#define TAU    2.0e-3f

static __device__ __forceinline__ void gload16(const void* g, void* l) {
    __builtin_amdgcn_global_load_lds(
        (const __attribute__((address_space(1))) void*)g,
        (__attribute__((address_space(3))) void*)l, 16, 0, 0);
}

// Register-select traversal (reference node idx = 2*idx + d; only nodes
// 0..15 are ever read).
static __device__ __forceinline__ int traverse(const float z[16], float* mn_out) {
    float a0 = z[0];
    bool d0 = a0 <= 0.f;
    float a1 = d0 ? z[1] : z[0];
    bool d1 = a1 <= 0.f;
    float a2 = d0 ? (d1 ? z[3] : z[2]) : (d1 ? z[1] : z[0]);
    bool d2 = a2 <= 0.f;
    float m0 = d2 ? z[1] : z[0], m1 = d2 ? z[3] : z[2];
    float m2 = d2 ? z[5] : z[4], m3 = d2 ? z[7] : z[6];
    float p0 = d1 ? m1 : m0, p1 = d1 ? m3 : m2;
    float a3 = d0 ? p1 : p0;
    bool d3 = a3 <= 0.f;
    float n0 = d3 ? z[1] : z[0],  n1 = d3 ? z[3] : z[2];
    float n2 = d3 ? z[5] : z[4],  n3 = d3 ? z[7] : z[6];
    float n4 = d3 ? z[9] : z[8],  n5 = d3 ? z[11] : z[10];
    float n6 = d3 ? z[13] : z[12], n7 = d3 ? z[15] : z[14];
    float q0 = d2 ? n1 : n0, q1 = d2 ? n3 : n2;
    float q2 = d2 ? n5 : n4, q3 = d2 ? n7 : n6;
    float r0 = d1 ? q1 : q0, r1 = d1 ? q3 : q2;
    float a4 = d0 ? r1 : r0;
    bool d4 = a4 <= 0.f;
    *mn_out = fminf(fminf(fminf(fabsf(a0), fabsf(a1)),
                          fminf(fabsf(a2), fabsf(a3))), fabsf(a4));
    return ((int)d0 << 4) | ((int)d1 << 3) | ((int)d2 << 2)
         | ((int)d3 << 1) | (int)d4;
}

// ---- K1: prep ---------------------------------------------------------------
// blocks 0..1023: X split hi/lo (layout: i = g*4096 + dq*128 + m*8 + e;
//   row = g*16+m, dims dq*8..+8).
// blocks 1024..1231: W image, 13 tg x [4 kq x (hi 16KB | lo 16KB)];
//   within: row*64 + (oct^(row&7))*8 elems; row = tree_in_group*16 + node.
// blocks 1232..2031: leaves -> bf16.
__global__ void prep(const float* __restrict__ x, const float* __restrict__ wf,
                     const float* __restrict__ lv,
                     bf16* __restrict__ xh, bf16* __restrict__ xl,
                     bf16* __restrict__ wimg, bf16* __restrict__ lv16) {
    if (blockIdx.x < 1024) {
        int i = blockIdx.x * 256 + threadIdx.x;       // 0 .. 262143
        int m  = i & 15;
        int dq = (i >> 4) & 31;
        int g  = i >> 9;
        const float* src = x + (size_t)(g * 16 + m) * ND + dq * 8;
        bf16x8 h8, l8;
#pragma unroll
        for (int e = 0; e < 8; ++e) {
            float f = src[e];
            bf16 h = (bf16)f;
            h8[e] = h;
            l8[e] = (bf16)(f - (float)h);
        }
        *(bf16x8*)(xh + (size_t)i * 8) = h8;
        *(bf16x8*)(xl + (size_t)i * 8) = l8;
    } else if (blockIdx.x < 1232) {
        int i = (blockIdx.x - 1024) * 256 + threadIdx.x;  // 0..53247
        int oct_g = i & 31;          // global k-octet 0..31
        int row   = (i >> 5) & 127;  // B row 0..127
        int tg    = i >> 12;         // tree group 0..12
        int tree  = tg * 8 + (row >> 4), node = row & 15;
        bf16x8 h8, l8;
        if (tree < NTREES) {
            const float* src = wf + ((size_t)tree * NNODES + node) * ND + oct_g * 8;
#pragma unroll
            for (int e = 0; e < 8; ++e) {
                float f = src[e];
                bf16 h = (bf16)f;
                h8[e] = h;
                l8[e] = (bf16)(f - (float)h);
            }
        } else {
#pragma unroll
            for (int e = 0; e < 8; ++e) { h8[e] = (bf16)0.f; l8[e] = (bf16)0.f; }
        }
        int kq = oct_g >> 3, oct = oct_g & 7, cp = oct ^ (row & 7);
        size_t b = (size_t)tg * 65536 + (size_t)kq * 16384 + row * 64 + cp * 8;
        *(bf16x8*)(wimg + b)        = h8;   // hi
        *(bf16x8*)(wimg + b + 8192) = l8;   // lo
    } else {
        int i = (blockIdx.x - 1232) * 256 + threadIdx.x;  // 0..204799
        lv16[i] = (bf16)lv[i];
    }
}

// ---- K2: GEMM + traversal + in-lane fixup -----------------------------------
// block: 256 samples x 8 trees (128 node-cols). 4 waves, each M=64, N=128.
// W slice (128KB) staged as two 64KB K-halves; 3 barriers total per block.
__global__ __launch_bounds__(256, 2) void forest_all(
    const bf16* __restrict__ xh, const bf16* __restrict__ xl,
    const bf16* __restrict__ wimg,
    const float* __restrict__ x,      // raw (fixup)
    const float* __restrict__ wf,     // raw (fixup)
    const float* __restrict__ bias,   // [100][31]
    unsigned char* __restrict__ idxb) // [8192][100]
{
    __shared__ char lds[65536];        // one K-half of W; scr overlays after

    const int tid  = threadIdx.x;
    const int wave = tid >> 6;
    const int lane = tid & 63;
    const int m    = lane & 15;
    const int q    = lane >> 4;

    const int lin  = blockIdx.x + gridDim.x * blockIdx.y;   // 0..415
    const int xcd  = lin & 7;
    const int slot = lin >> 3;         // 0..51
    const int mg   = xcd * 4 + (slot / 13);
    const int tg   = slot % 13;        // tree-group of 8 (tg 12: 4 real)

    f32x4 acc[4][8];
#pragma unroll
    for (int mi = 0; mi < 4; ++mi)
#pragma unroll
        for (int ni = 0; ni < 8; ++ni)
            acc[mi][ni] = (f32x4){0.f, 0.f, 0.f, 0.f};

    size_t abase[4];
#pragma unroll
    for (int mi = 0; mi < 4; ++mi)
        abase[mi] = (size_t)(mg * 16 + wave * 4 + mi) * 4096 + lane * 8;

    const bf16* wsrc = wimg + (size_t)tg * 65536;

    // ---- stage K-half 0 (quarters 0,1 = 64KB) once; prefetch A kk=0
#pragma unroll
    for (int j = 0; j < 16; ++j) {
        int idx = j * 256 + tid;           // 4096 16B chunks
        gload16(wsrc + idx * 8, lds + idx * 16);
    }
    bf16x8 cah[4], cal[4], nah[4], nal[4];
#pragma unroll
    for (int mi = 0; mi < 4; ++mi) {
        cah[mi] = *(const bf16x8*)(xh + abase[mi]);
        cal[mi] = *(const bf16x8*)(xl + abase[mi]);
    }
    __syncthreads();

    // ---- rolled K-loop, no staging in steady state
#pragma unroll 1
    for (int kk = 0; kk < 8; ++kk) {
        if (kk == 4) {                     // swap to K-half 1 (quarters 2,3)
            __syncthreads();
#pragma unroll
            for (int j = 0; j < 16; ++j) {
                int idx = j * 256 + tid;
                gload16(wsrc + 32768 + idx * 8, lds + idx * 16);
            }
            __syncthreads();
        }
        const bf16* bufc = (const bf16*)lds + ((kk >> 1) & 1) * 16384;
        const int kkq = kk & 1;
        if (kk < 7) {                      // prefetch next A batch (global)
#pragma unroll
            for (int mi = 0; mi < 4; ++mi) {
                nah[mi] = *(const bf16x8*)(xh + abase[mi] + (kk + 1) * 512);
                nal[mi] = *(const bf16x8*)(xl + abase[mi] + (kk + 1) * 512);
            }
        }
#pragma unroll
        for (int ni = 0; ni < 8; ++ni) {
            const int n  = ni * 16 + m;
            const int cp = (kkq * 4 + q) ^ (m & 7);
            bf16x8 bh = *(const bf16x8*)(bufc + n * 64 + cp * 8);
            bf16x8 bl = *(const bf16x8*)(bufc + 8192 + n * 64 + cp * 8);
            // 3 passes of 4 independent MFMA chains (dep distance 4 instrs)
#pragma unroll
            for (int mi = 0; mi < 4; ++mi)
                acc[mi][ni] = __builtin_amdgcn_mfma_f32_16x16x32_bf16(cal[mi], bh, acc[mi][ni], 0, 0, 0);
#pragma unroll
            for (int mi = 0; mi < 4; ++mi)
                acc[mi][ni] = __builtin_amdgcn_mfma_f32_16x16x32_bf16(cah[mi], bl, acc[mi][ni], 0, 0, 0);
#pragma unroll
            for (int mi = 0; mi < 4; ++mi)
                acc[mi][ni] = __builtin_amdgcn_mfma_f32_16x16x32_bf16(cah[mi], bh, acc[mi][ni], 0, 0, 0);
        }
#pragma unroll
        for (int mi = 0; mi < 4; ++mi) { cah[mi] = nah[mi]; cal[mi] = nal[mi]; }
    }
    __syncthreads();   // LDS reuse as epilogue scratch

    // ---- epilogue: per-wave transpose via LDS, traversal, in-lane fp64 fixup
    float biasv[8];
#pragma unroll
    for (int ni = 0; ni < 8; ++ni) {
        int tree = tg * 8 + ni;
        biasv[ni] = (tree < NTREES) ? bias[(size_t)tree * NNODES + m] : 0.f;
    }

    float* ws_ = (float*)lds + wave * 1280;    // 64 rows x 20 floats per wave
    const int sg = mg * 256 + wave * 64 + lane;
    unsigned int pk0 = 0, pk1 = 0;
#pragma unroll
    for (int ni = 0; ni < 8; ++ni) {
        // D layout: col = m (node), row-in-16 = q*4 + r (sample)
#pragma unroll
        for (int mi = 0; mi < 4; ++mi)
#pragma unroll
            for (int r = 0; r < 4; ++r)
                ws_[(mi * 16 + q * 4 + r) * 20 + m] = acc[mi][ni][r] + biasv[ni];
        f32x4 z0 = *(f32x4*)&ws_[lane * 20];
        f32x4 z1 = *(f32x4*)&ws_[lane * 20 + 4];
        f32x4 z2 = *(f32x4*)&ws_[lane * 20 + 8];
        f32x4 z3 = *(f32x4*)&ws_[lane * 20 + 12];
        float z[16] = {z0[0], z0[1], z0[2], z0[3], z1[0], z1[1], z1[2], z1[3],
                       z2[0], z2[1], z2[2], z2[3], z3[0], z3[1], z3[2], z3[3]};
        float mn;
        int leaf = traverse(z, &mn);
        const int tree = tg * 8 + ni;
        if (tree < NTREES && mn < TAU) {   // rare; dummy trees must not enter
            const float* xr = x + (size_t)sg * ND;
            float zc[16];
#pragma unroll
            for (int nd = 0; nd < 16; ++nd) zc[nd] = z[nd];
#pragma unroll
            for (int nd = 0; nd < 16; ++nd) {
                if (fabsf(z[nd]) < TAU) {
                    const float* wr = wf + ((size_t)tree * NNODES + nd) * ND;
                    double s0 = 0.0, s1 = 0.0;
#pragma unroll 4
                    for (int k2 = 0; k2 < 32; ++k2) {
                        f32x4 xv = *(const f32x4*)(xr + k2 * 8);
                        f32x4 wv = *(const f32x4*)(wr + k2 * 8);
                        f32x4 xu = *(const f32x4*)(xr + k2 * 8 + 4);
                        f32x4 wu = *(const f32x4*)(wr + k2 * 8 + 4);
                        s0 += (double)xv[0] * wv[0] + (double)xv[1] * wv[1]
                            + (double)xv[2] * wv[2] + (double)xv[3] * wv[3];
                        s1 += (double)xu[0] * wu[0] + (double)xu[1] * wu[1]
                            + (double)xu[2] * wu[2] + (double)xu[3] * wu[3];
                    }
                    double zt = s0 + s1 + (double)bias[(size_t)tree * NNODES + nd];
                    zc[nd] = (zt <= 0.0) ? -1.f : 1.f;
                }
            }
            float mn2;
            leaf = traverse(zc, &mn2);
        }
        if (ni < 4) pk0 |= (unsigned)leaf << (8 * ni);
        else        pk1 |= (unsigned)leaf << (8 * (ni - 4));
    }
    unsigned char* dst = idxb + (size_t)sg * NTREES + tg * 8;
    *(unsigned int*)dst = pk0;
    if (tg < 12) *(unsigned int*)(dst + 4) = pk1;
}

// ---- K3: leaf gather (bf16 leaves) + forest mean ----------------------------
__global__ void leaf_gather(const unsigned char* __restrict__ idxb,
                            const bf16* __restrict__ lv16,
                            float* __restrict__ out) {
    const int wave = threadIdx.x >> 6;
    const int lane = threadIdx.x & 63;
    const int s = blockIdx.x * 4 + wave;
    unsigned int rw = 0;
    if (lane < 25) rw = *(const unsigned int*)(idxb + (size_t)s * NTREES + lane * 4);
    float acc = 0.f;
#pragma unroll 10
    for (int t = 0; t < NTREES; ++t) {
        unsigned int wrd = __shfl(rw, t >> 2);
        int li = (wrd >> ((t & 3) * 8)) & 255;
        acc += (float)lv16[((size_t)t * NLEAF + li) * NCLS + lane];
    }
    out[(size_t)s * NCLS + lane] = acc * 0.01f;
}

// ---------------------------------------------------------------------------
extern "C" void kernel_launch(void* const* d_in, const int* in_sizes, int n_in,
                              void* d_out, int out_size, void* d_ws, size_t ws_size,
                              hipStream_t stream) {
    const float* x  = (const float*)d_in[0];   // [8192,256]
    const float* nw = (const float*)d_in[1];   // [100,31,256]
    const float* nb = (const float*)d_in[2];   // [100,31]
    const float* lv = (const float*)d_in[3];   // [100,32,64]
    float* out = (float*)d_out;

    char* ws = (char*)d_ws;
    bf16* xh   = (bf16*)(ws + 0);                           // 4,194,304
    bf16* xl   = (bf16*)(ws + 4194304);                     // 4,194,304
    bf16* wimg = (bf16*)(ws + 8388608);                     // 1,703,936
    unsigned char* idxb = (unsigned char*)(ws + 10092544);  //   819,200
    bf16* lv16 = (bf16*)(ws + 10911744);                    //   409,600
    if (ws_size < (size_t)11321344) return;

    prep<<<2032, 256, 0, stream>>>(x, nw, lv, xh, xl, wimg, lv16);
    forest_all<<<dim3(13, 32), 256, 0, stream>>>(xh, xl, wimg, x, nw, nb, idxb);
    leaf_gather<<<NB / 4, 256, 0, stream>>>(idxb, lv16, out);
}

// Round 8
// 121.423 us; speedup vs baseline: 1.0540x; 1.0540x over previous
//
#include <hip/hip_runtime.h>

// ---------------------------------------------------------------------------
// RandomForest: 100 trees, depth 5, D=256, B=8192, C=64.
// r8 = r7 resubmit (container-level infra failure, no kernel verdict).
// LOCALIZATION SPLIT: forest_all (stuck 45-52us across 6 structural
// rewrites, all pipes <20%) is split at the GEMM/epilogue boundary:
//   gemm_z    = r6 K-loop verbatim, epilogue -> bias + coalesced f32 z store
//   traverse_k = per-(sample,tree) traversal + cold fp64 fixup from z
// z roundtrip = 2x52MB (L3-resident). rocprof tells us which side owned the
// missing 40us. Branch (a): epilogue was it -> total ~90-100.
// Branch (b): gemm_z still ~40 -> core is the culprit, epilogue exonerated.
// prep & leaf_gather unchanged from r6.
// ---------------------------------------------------------------------------

typedef __bf16 bf16;
typedef __attribute__((ext_vector_type(8))) __bf16 bf16x8;
typedef __attribute__((ext_vector_type(4))) float f32x4;

#define NTREES 100
#define NB     8192
#define ND     256
#define NNODES 31
#define NLEAF  32
#define NCLS   64
#define TAU    2.0e-3f

static __device__ __forceinline__ void gload16(const void* g, void* l) {
    __builtin_amdgcn_global_load_lds(
        (const __attribute__((address_space(1))) void*)g,
        (__attribute__((address_space(3))) void*)l, 16, 0, 0);
}

// Register-select traversal (reference node idx = 2*idx + d; only nodes
// 0..15 are ever read).
static __device__ __forceinline__ int traverse(const float z[16], float* mn_out) {
    float a0 = z[0];
    bool d0 = a0 <= 0.f;
    float a1 = d0 ? z[1] : z[0];
    bool d1 = a1 <= 0.f;
    float a2 = d0 ? (d1 ? z[3] : z[2]) : (d1 ? z[1] : z[0]);
    bool d2 = a2 <= 0.f;
    float m0 = d2 ? z[1] : z[0], m1 = d2 ? z[3] : z[2];
    float m2 = d2 ? z[5] : z[4], m3 = d2 ? z[7] : z[6];
    float p0 = d1 ? m1 : m0, p1 = d1 ? m3 : m2;
    float a3 = d0 ? p1 : p0;
    bool d3 = a3 <= 0.f;
    float n0 = d3 ? z[1] : z[0],  n1 = d3 ? z[3] : z[2];
    float n2 = d3 ? z[5] : z[4],  n3 = d3 ? z[7] : z[6];
    float n4 = d3 ? z[9] : z[8],  n5 = d3 ? z[11] : z[10];
    float n6 = d3 ? z[13] : z[12], n7 = d3 ? z[15] : z[14];
    float q0 = d2 ? n1 : n0, q1 = d2 ? n3 : n2;
    float q2 = d2 ? n5 : n4, q3 = d2 ? n7 : n6;
    float r0 = d1 ? q1 : q0, r1 = d1 ? q3 : q2;
    float a4 = d0 ? r1 : r0;
    bool d4 = a4 <= 0.f;
    *mn_out = fminf(fminf(fminf(fabsf(a0), fabsf(a1)),
                          fminf(fabsf(a2), fabsf(a3))), fabsf(a4));
    return ((int)d0 << 4) | ((int)d1 << 3) | ((int)d2 << 2)
         | ((int)d3 << 1) | (int)d4;
}

// ---- K1: prep (unchanged from r6) -------------------------------------------
__global__ void prep(const float* __restrict__ x, const float* __restrict__ wf,
                     const float* __restrict__ lv,
                     bf16* __restrict__ xh, bf16* __restrict__ xl,
                     bf16* __restrict__ wimg, bf16* __restrict__ lv16) {
    if (blockIdx.x < 1024) {
        int i = blockIdx.x * 256 + threadIdx.x;       // 0 .. 262143
        int m  = i & 15;
        int dq = (i >> 4) & 31;
        int g  = i >> 9;
        const float* src = x + (size_t)(g * 16 + m) * ND + dq * 8;
        bf16x8 h8, l8;
#pragma unroll
        for (int e = 0; e < 8; ++e) {
            float f = src[e];
            bf16 h = (bf16)f;
            h8[e] = h;
            l8[e] = (bf16)(f - (float)h);
        }
        *(bf16x8*)(xh + (size_t)i * 8) = h8;
        *(bf16x8*)(xl + (size_t)i * 8) = l8;
    } else if (blockIdx.x < 1232) {
        int i = (blockIdx.x - 1024) * 256 + threadIdx.x;  // 0..53247
        int oct_g = i & 31;          // global k-octet 0..31
        int row   = (i >> 5) & 127;  // B row 0..127
        int tg    = i >> 12;         // tree group 0..12
        int tree  = tg * 8 + (row >> 4), node = row & 15;
        bf16x8 h8, l8;
        if (tree < NTREES) {
            const float* src = wf + ((size_t)tree * NNODES + node) * ND + oct_g * 8;
#pragma unroll
            for (int e = 0; e < 8; ++e) {
                float f = src[e];
                bf16 h = (bf16)f;
                h8[e] = h;
                l8[e] = (bf16)(f - (float)h);
            }
        } else {
#pragma unroll
            for (int e = 0; e < 8; ++e) { h8[e] = (bf16)0.f; l8[e] = (bf16)0.f; }
        }
        int kq = oct_g >> 3, oct = oct_g & 7, cp = oct ^ (row & 7);
        size_t b = (size_t)tg * 65536 + (size_t)kq * 16384 + row * 64 + cp * 8;
        *(bf16x8*)(wimg + b)        = h8;   // hi
        *(bf16x8*)(wimg + b + 8192) = l8;   // lo
    } else {
        int i = (blockIdx.x - 1232) * 256 + threadIdx.x;  // 0..204799
        lv16[i] = (bf16)lv[i];
    }
}

// ---- K2a: pure GEMM -> z scores ---------------------------------------------
// block: 256 samples x 8 trees. 4 waves, each M=64, N=128. K-loop = r6
// verbatim. Epilogue = bias add + coalesced f32 store, nothing else.
__global__ __launch_bounds__(256, 2) void gemm_z(
    const bf16* __restrict__ xh, const bf16* __restrict__ xl,
    const bf16* __restrict__ wimg,
    const float* __restrict__ bias,   // [100][31]
    float* __restrict__ zbuf)         // [8192][100][16]
{
    __shared__ char lds[65536];        // one K-half of W

    const int tid  = threadIdx.x;
    const int wave = tid >> 6;
    const int lane = tid & 63;
    const int m    = lane & 15;
    const int q    = lane >> 4;

    const int lin  = blockIdx.x + gridDim.x * blockIdx.y;   // 0..415
    const int xcd  = lin & 7;
    const int slot = lin >> 3;         // 0..51
    const int mg   = xcd * 4 + (slot / 13);
    const int tg   = slot % 13;        // tree-group of 8 (tg 12: 4 real)

    f32x4 acc[4][8];
#pragma unroll
    for (int mi = 0; mi < 4; ++mi)
#pragma unroll
        for (int ni = 0; ni < 8; ++ni)
            acc[mi][ni] = (f32x4){0.f, 0.f, 0.f, 0.f};

    size_t abase[4];
#pragma unroll
    for (int mi = 0; mi < 4; ++mi)
        abase[mi] = (size_t)(mg * 16 + wave * 4 + mi) * 4096 + lane * 8;

    const bf16* wsrc = wimg + (size_t)tg * 65536;

    // ---- stage K-half 0 (64KB) once; prefetch A kk=0
#pragma unroll
    for (int j = 0; j < 16; ++j) {
        int idx = j * 256 + tid;           // 4096 16B chunks
        gload16(wsrc + idx * 8, lds + idx * 16);
    }
    bf16x8 cah[4], cal[4], nah[4], nal[4];
#pragma unroll
    for (int mi = 0; mi < 4; ++mi) {
        cah[mi] = *(const bf16x8*)(xh + abase[mi]);
        cal[mi] = *(const bf16x8*)(xl + abase[mi]);
    }
    __syncthreads();

#pragma unroll 1
    for (int kk = 0; kk < 8; ++kk) {
        if (kk == 4) {                     // swap to K-half 1
            __syncthreads();
#pragma unroll
            for (int j = 0; j < 16; ++j) {
                int idx = j * 256 + tid;
                gload16(wsrc + 32768 + idx * 8, lds + idx * 16);
            }
            __syncthreads();
        }
        const bf16* bufc = (const bf16*)lds + ((kk >> 1) & 1) * 16384;
        const int kkq = kk & 1;
        if (kk < 7) {                      // prefetch next A batch (global)
#pragma unroll
            for (int mi = 0; mi < 4; ++mi) {
                nah[mi] = *(const bf16x8*)(xh + abase[mi] + (kk + 1) * 512);
                nal[mi] = *(const bf16x8*)(xl + abase[mi] + (kk + 1) * 512);
            }
        }
#pragma unroll
        for (int ni = 0; ni < 8; ++ni) {
            const int n  = ni * 16 + m;
            const int cp = (kkq * 4 + q) ^ (m & 7);
            bf16x8 bh = *(const bf16x8*)(bufc + n * 64 + cp * 8);
            bf16x8 bl = *(const bf16x8*)(bufc + 8192 + n * 64 + cp * 8);
#pragma unroll
            for (int mi = 0; mi < 4; ++mi)
                acc[mi][ni] = __builtin_amdgcn_mfma_f32_16x16x32_bf16(cal[mi], bh, acc[mi][ni], 0, 0, 0);
#pragma unroll
            for (int mi = 0; mi < 4; ++mi)
                acc[mi][ni] = __builtin_amdgcn_mfma_f32_16x16x32_bf16(cah[mi], bl, acc[mi][ni], 0, 0, 0);
#pragma unroll
            for (int mi = 0; mi < 4; ++mi)
                acc[mi][ni] = __builtin_amdgcn_mfma_f32_16x16x32_bf16(cah[mi], bh, acc[mi][ni], 0, 0, 0);
        }
#pragma unroll
        for (int mi = 0; mi < 4; ++mi) { cah[mi] = nah[mi]; cal[mi] = nal[mi]; }
    }

    // ---- minimal epilogue: bias + store z in [sample][tree][node] f32
    float biasv[8];
#pragma unroll
    for (int ni = 0; ni < 8; ++ni) {
        int tree = tg * 8 + ni;
        biasv[ni] = (tree < NTREES) ? bias[(size_t)tree * NNODES + m] : 0.f;
    }
    const int sbase = mg * 256 + wave * 64;
#pragma unroll
    for (int ni = 0; ni < 8; ++ni) {
        const int t = tg * 8 + ni;
        if (t < NTREES) {
#pragma unroll
            for (int mi = 0; mi < 4; ++mi)
#pragma unroll
                for (int r = 0; r < 4; ++r) {
                    int s = sbase + mi * 16 + q * 4 + r;
                    zbuf[((size_t)s * NTREES + t) * 16 + m] = acc[mi][ni][r] + biasv[ni];
                }
        }
    }
}

// ---- K2b: traversal + in-lane fp64 fixup from z -----------------------------
// block: 256 threads = 2 samples x 128 lanes (t = tid&127, active t<100).
__global__ void traverse_k(const float* __restrict__ zbuf,
                           const float* __restrict__ x,
                           const float* __restrict__ wf,
                           const float* __restrict__ bias,
                           unsigned char* __restrict__ idxb) {
    const int t = threadIdx.x & 127;
    const int s = blockIdx.x * 2 + (threadIdx.x >> 7);
    if (t >= NTREES) return;
    const float* zr = zbuf + ((size_t)s * NTREES + t) * 16;
    f32x4 z0 = *(const f32x4*)(zr);
    f32x4 z1 = *(const f32x4*)(zr + 4);
    f32x4 z2 = *(const f32x4*)(zr + 8);
    f32x4 z3 = *(const f32x4*)(zr + 12);
    float z[16] = {z0[0], z0[1], z0[2], z0[3], z1[0], z1[1], z1[2], z1[3],
                   z2[0], z2[1], z2[2], z2[3], z3[0], z3[1], z3[2], z3[3]};
    float mn;
    int leaf = traverse(z, &mn);
    if (mn < TAU) {                        // rare: fp64 re-derivation
        const float* xr = x + (size_t)s * ND;
        float zc[16];
#pragma unroll
        for (int nd = 0; nd < 16; ++nd) zc[nd] = z[nd];
#pragma unroll
        for (int nd = 0; nd < 16; ++nd) {
            if (fabsf(z[nd]) < TAU) {
                const float* wr = wf + ((size_t)t * NNODES + nd) * ND;
                double s0 = 0.0, s1 = 0.0;
#pragma unroll 4
                for (int k2 = 0; k2 < 32; ++k2) {
                    f32x4 xv = *(const f32x4*)(xr + k2 * 8);
                    f32x4 wv = *(const f32x4*)(wr + k2 * 8);
                    f32x4 xu = *(const f32x4*)(xr + k2 * 8 + 4);
                    f32x4 wu = *(const f32x4*)(wr + k2 * 8 + 4);
                    s0 += (double)xv[0] * wv[0] + (double)xv[1] * wv[1]
                        + (double)xv[2] * wv[2] + (double)xv[3] * wv[3];
                    s1 += (double)xu[0] * wu[0] + (double)xu[1] * wu[1]
                        + (double)xu[2] * wu[2] + (double)xu[3] * wu[3];
                }
                double zt = s0 + s1 + (double)bias[(size_t)t * NNODES + nd];
                zc[nd] = (zt <= 0.0) ? -1.f : 1.f;
            }
        }
        float mn2;
        leaf = traverse(zc, &mn2);
    }
    idxb[(size_t)s * NTREES + t] = (unsigned char)leaf;
}

// ---- K3: leaf gather (bf16 leaves) + forest mean (unchanged) ----------------
__global__ void leaf_gather(const unsigned char* __restrict__ idxb,
                            const bf16* __restrict__ lv16,
                            float* __restrict__ out) {
    const int wave = threadIdx.x >> 6;
    const int lane = threadIdx.x & 63;
    const int s = blockIdx.x * 4 + wave;
    unsigned int rw = 0;
    if (lane < 25) rw = *(const unsigned int*)(idxb + (size_t)s * NTREES + lane * 4);
    float acc = 0.f;
#pragma unroll 10
    for (int t = 0; t < NTREES; ++t) {
        unsigned int wrd = __shfl(rw, t >> 2);
        int li = (wrd >> ((t & 3) * 8)) & 255;
        acc += (float)lv16[((size_t)t * NLEAF + li) * NCLS + lane];
    }
    out[(size_t)s * NCLS + lane] = acc * 0.01f;
}

// ---------------------------------------------------------------------------
extern "C" void kernel_launch(void* const* d_in, const int* in_sizes, int n_in,
                              void* d_out, int out_size, void* d_ws, size_t ws_size,
                              hipStream_t stream) {
    const float* x  = (const float*)d_in[0];   // [8192,256]
    const float* nw = (const float*)d_in[1];   // [100,31,256]
    const float* nb = (const float*)d_in[2];   // [100,31]
    const float* lv = (const float*)d_in[3];   // [100,32,64]
    float* out = (float*)d_out;

    char* ws = (char*)d_ws;
    bf16* xh   = (bf16*)(ws + 0);                           //  4,194,304
    bf16* xl   = (bf16*)(ws + 4194304);                     //  4,194,304
    bf16* wimg = (bf16*)(ws + 8388608);                     //  1,703,936
    unsigned char* idxb = (unsigned char*)(ws + 10092544);  //    819,200
    bf16* lv16 = (bf16*)(ws + 10911744);                    //    409,600
    float* zbuf = (float*)(ws + 11321344);                  // 52,428,800
    if (ws_size < (size_t)63750144) return;

    prep<<<2032, 256, 0, stream>>>(x, nw, lv, xh, xl, wimg, lv16);
    gemm_z<<<dim3(13, 32), 256, 0, stream>>>(xh, xl, wimg, nb, zbuf);
    traverse_k<<<NB / 2, 256, 0, stream>>>(zbuf, x, nw, nb, idxb);
    leaf_gather<<<NB / 4, 256, 0, stream>>>(idxb, lv16, out);
}

// Round 9
// 114.462 us; speedup vs baseline: 1.1181x; 1.0608x over previous
//
#include <hip/hip_runtime.h>

// ---------------------------------------------------------------------------
// RandomForest: 100 trees, depth 5, D=256, B=8192, C=64.
// r9 = r1 (best measured, 108.4us) + in-lane fp64 fixup (drops fixup_kernel,
// queue, qcount). Accounting model (closed in r8): timed window = ~87.3us of
// harness poison fills (2x256MiB, untouchable) + our kernels; rocprof
// per-dispatch times are replay-inflated ~1.5-2x. r0/r1 were the best configs
// all along (~21us controllable); r2-r8 restructures all regressed.
// Changes vs r1: forest epilogue does rare fp64 re-derivation inline
// (mechanism proven r4/r5/r8); prep loses qcount; 3 kernels total.
// ---------------------------------------------------------------------------

typedef __bf16 bf16;
typedef __attribute__((ext_vector_type(8))) __bf16 bf16x8;
typedef __attribute__((ext_vector_type(4))) float f32x4;

#define NTREES 100
#define NB     8192
#define ND     256
#define NNODES 31
#define NLEAF  32
#define NCLS   64
#define TAU    2.0e-3f

static __device__ __forceinline__ void gload16(const void* g, void* l) {
    __builtin_amdgcn_global_load_lds(
        (const __attribute__((address_space(1))) void*)g,
        (__attribute__((address_space(3))) void*)l, 16, 0, 0);
}

// Register-select traversal (reference node idx = 2*idx + d; only nodes
// 0..15 are ever read).
static __device__ __forceinline__ int traverse(const float z[16], float* mn_out) {
    float a0 = z[0];
    bool d0 = a0 <= 0.f;
    float a1 = d0 ? z[1] : z[0];
    bool d1 = a1 <= 0.f;
    float a2 = d0 ? (d1 ? z[3] : z[2]) : (d1 ? z[1] : z[0]);
    bool d2 = a2 <= 0.f;
    float m0 = d2 ? z[1] : z[0], m1 = d2 ? z[3] : z[2];
    float m2 = d2 ? z[5] : z[4], m3 = d2 ? z[7] : z[6];
    float p0 = d1 ? m1 : m0, p1 = d1 ? m3 : m2;
    float a3 = d0 ? p1 : p0;
    bool d3 = a3 <= 0.f;
    float n0 = d3 ? z[1] : z[0],  n1 = d3 ? z[3] : z[2];
    float n2 = d3 ? z[5] : z[4],  n3 = d3 ? z[7] : z[6];
    float n4 = d3 ? z[9] : z[8],  n5 = d3 ? z[11] : z[10];
    float n6 = d3 ? z[13] : z[12], n7 = d3 ? z[15] : z[14];
    float q0 = d2 ? n1 : n0, q1 = d2 ? n3 : n2;
    float q2 = d2 ? n5 : n4, q3 = d2 ? n7 : n6;
    float r0 = d1 ? q1 : q0, r1 = d1 ? q3 : q2;
    float a4 = d0 ? r1 : r0;
    bool d4 = a4 <= 0.f;
    *mn_out = fminf(fminf(fminf(fabsf(a0), fabsf(a1)),
                          fminf(fabsf(a2), fabsf(a3))), fabsf(a4));
    return ((int)d0 << 4) | ((int)d1 << 3) | ((int)d2 << 2)
         | ((int)d3 << 1) | (int)d4;
}

// ---- K1: prep (r1 verbatim, minus qcount) -----------------------------------
// blocks 0..1023: X split (layout: i = g*4096 + dq*128 + m*8 + e).
// blocks 1024..1231: W image, 13 tg x [4 kq x (hi 16KB | lo 16KB)];
//   within: row*64 + (oct^(row&7))*8, oct = k-octet within quarter.
// blocks 1232..2031: leaves -> bf16.
__global__ void prep(const float* __restrict__ x, const float* __restrict__ wf,
                     const float* __restrict__ lv,
                     bf16* __restrict__ xh, bf16* __restrict__ xl,
                     bf16* __restrict__ wimg, bf16* __restrict__ lv16) {
    if (blockIdx.x < 1024) {
        int i = blockIdx.x * 256 + threadIdx.x;       // 0 .. 262143
        int m  = i & 15;
        int dq = (i >> 4) & 31;
        int g  = i >> 9;
        const float* src = x + (size_t)(g * 16 + m) * ND + dq * 8;
        bf16x8 h8, l8;
#pragma unroll
        for (int e = 0; e < 8; ++e) {
            float f = src[e];
            bf16 h = (bf16)f;
            h8[e] = h;
            l8[e] = (bf16)(f - (float)h);
        }
        *(bf16x8*)(xh + (size_t)i * 8) = h8;
        *(bf16x8*)(xl + (size_t)i * 8) = l8;
    } else if (blockIdx.x < 1232) {
        int i = (blockIdx.x - 1024) * 256 + threadIdx.x;  // 0..53247
        int oct_g = i & 31;          // global k-octet 0..31
        int row   = (i >> 5) & 127;  // B row 0..127
        int tg    = i >> 12;         // tree group 0..12
        int tree  = tg * 8 + (row >> 4), node = row & 15;
        bf16x8 h8, l8;
        if (tree < NTREES) {
            const float* src = wf + ((size_t)tree * NNODES + node) * ND + oct_g * 8;
#pragma unroll
            for (int e = 0; e < 8; ++e) {
                float f = src[e];
                bf16 h = (bf16)f;
                h8[e] = h;
                l8[e] = (bf16)(f - (float)h);
            }
        } else {
#pragma unroll
            for (int e = 0; e < 8; ++e) { h8[e] = (bf16)0.f; l8[e] = (bf16)0.f; }
        }
        int kq = oct_g >> 3, oct = oct_g & 7, cp = oct ^ (row & 7);
        size_t b = (size_t)tg * 65536 + (size_t)kq * 16384 + row * 64 + cp * 8;
        *(bf16x8*)(wimg + b)        = h8;   // hi
        *(bf16x8*)(wimg + b + 8192) = l8;   // lo
    } else {
        int i = (blockIdx.x - 1232) * 256 + threadIdx.x;  // 0..204799
        lv16[i] = (bf16)lv[i];
    }
}

// ---- K2: GEMM + traversal + in-lane fixup -----------------------------------
// block: 256 samples x 8 trees (128 cols). 8 waves, each M=32, N=128. (r1)
__global__ __launch_bounds__(512, 4) void forest_all(
    const bf16* __restrict__ xh, const bf16* __restrict__ xl,
    const bf16* __restrict__ wimg,
    const float* __restrict__ x,      // raw (fixup)
    const float* __restrict__ wf,     // raw (fixup)
    const float* __restrict__ bias,   // [100][31]
    unsigned char* __restrict__ idxb) // [8192][100]
{
    __shared__ char lds[65536];            // two 32KB B buffers; scr overlays after

    const int tid  = threadIdx.x;
    const int wave = tid >> 6;             // 0..7
    const int lane = tid & 63;
    const int m    = lane & 15;
    const int q    = lane >> 4;

    const int lin  = blockIdx.x + gridDim.x * blockIdx.y;   // 0..415
    const int xcd  = lin & 7;
    const int slot = lin >> 3;             // 0..51
    const int mg   = xcd * 4 + (slot / 13);
    const int tg   = slot % 13;            // tree-group of 8 (tg 12: 4 real)

    f32x4 acc[2][8];
#pragma unroll
    for (int mi = 0; mi < 2; ++mi)
#pragma unroll
        for (int ni = 0; ni < 8; ++ni)
            acc[mi][ni] = (f32x4){0.f, 0.f, 0.f, 0.f};

    size_t abase[2];
#pragma unroll
    for (int mi = 0; mi < 2; ++mi)
        abase[mi] = (size_t)(mg * 16 + wave * 2 + mi) * 4096 + lane * 8;

    const bf16* wsrc = wimg + (size_t)tg * 65536;

    // ---- stage kq=0 into buf0, then loop with 1-ahead async staging
#pragma unroll
    for (int j = 0; j < 4; ++j) {
        int idx = j * 512 + tid;           // 2048 16B chunks = 32KB
        gload16(wsrc + idx * 8, lds + idx * 16);
    }
    __syncthreads();

#pragma unroll
    for (int kq = 0; kq < 4; ++kq) {
        const char* bufc = lds + (kq & 1) * 32768;
        if (kq < 3) {                      // async-stage next quarter
            char* bufn = lds + ((kq + 1) & 1) * 32768;
#pragma unroll
            for (int j = 0; j < 4; ++j) {
                int idx = j * 512 + tid;
                gload16(wsrc + (size_t)(kq + 1) * 16384 + idx * 8, bufn + idx * 16);
            }
        }
#pragma unroll
        for (int kkq = 0; kkq < 2; ++kkq) {
            const int kk = kq * 2 + kkq;
            bf16x8 cah[2], cal[2];
#pragma unroll
            for (int mi = 0; mi < 2; ++mi) {
                cah[mi] = *(const bf16x8*)(xh + abase[mi] + kk * 512);
                cal[mi] = *(const bf16x8*)(xl + abase[mi] + kk * 512);
            }
#pragma unroll
            for (int ni = 0; ni < 8; ++ni) {
                const int n  = ni * 16 + m;
                const int cp = (kkq * 4 + q) ^ (m & 7);
                bf16x8 bh = *(const bf16x8*)((const bf16*)bufc + n * 64 + cp * 8);
                bf16x8 bl = *(const bf16x8*)((const bf16*)bufc + 8192 + n * 64 + cp * 8);
#pragma unroll
                for (int mi = 0; mi < 2; ++mi) {
                    acc[mi][ni] = __builtin_amdgcn_mfma_f32_16x16x32_bf16(cal[mi], bh, acc[mi][ni], 0, 0, 0);
                    acc[mi][ni] = __builtin_amdgcn_mfma_f32_16x16x32_bf16(cah[mi], bl, acc[mi][ni], 0, 0, 0);
                    acc[mi][ni] = __builtin_amdgcn_mfma_f32_16x16x32_bf16(cah[mi], bh, acc[mi][ni], 0, 0, 0);
                }
            }
        }
        __syncthreads();   // next buffer staged AND current fully consumed
    }

    // ---- epilogue (r1): per-wave transpose via LDS; 2 ni slots per pass.
    // Lane halves: p = lane>>5 owns ni quad {p*4..p*4+3}; r = lane&31 = row.
    float biasv[8];
#pragma unroll
    for (int ni = 0; ni < 8; ++ni) {
        int tree = tg * 8 + ni;
        biasv[ni] = (tree < NTREES) ? bias[(size_t)tree * NNODES + m] : 0.f;
    }

    float* ws_ = (float*)lds + wave * 1408;        // 32*44 floats per wave
    const int p = lane >> 5;
    const int r = lane & 31;
    const int sg = mg * 256 + wave * 32 + r;
    unsigned int pk = 0;
#pragma unroll
    for (int j = 0; j < 4; ++j) {
        // write two ni slots: slot0 = ni j, slot1 = ni j+4
#pragma unroll
        for (int mi = 0; mi < 2; ++mi)
#pragma unroll
            for (int rr = 0; rr < 4; ++rr) {
                int row = mi * 16 + q * 4 + rr;
                ws_[row * 44 + m]      = acc[mi][j][rr]     + biasv[j];
                ws_[row * 44 + 20 + m] = acc[mi][j + 4][rr] + biasv[j + 4];
            }
        f32x4 z0 = *(f32x4*)&ws_[r * 44 + p * 20];
        f32x4 z1 = *(f32x4*)&ws_[r * 44 + p * 20 + 4];
        f32x4 z2 = *(f32x4*)&ws_[r * 44 + p * 20 + 8];
        f32x4 z3 = *(f32x4*)&ws_[r * 44 + p * 20 + 12];
        float z[16] = {z0[0], z0[1], z0[2], z0[3], z1[0], z1[1], z1[2], z1[3],
                       z2[0], z2[1], z2[2], z2[3], z3[0], z3[1], z3[2], z3[3]};
        float mn;
        int leaf = traverse(z, &mn);
        const int tree = tg * 8 + (j + p * 4);
        if (tree < NTREES && mn < TAU) {   // rare in-lane fp64 re-derivation
            const float* xr = x + (size_t)sg * ND;
            float zc[16];
#pragma unroll
            for (int nd = 0; nd < 16; ++nd) zc[nd] = z[nd];
#pragma unroll
            for (int nd = 0; nd < 16; ++nd) {
                if (fabsf(z[nd]) < TAU) {
                    const float* wr = wf + ((size_t)tree * NNODES + nd) * ND;
                    double s0 = 0.0, s1 = 0.0;
#pragma unroll 4
                    for (int k2 = 0; k2 < 32; ++k2) {
                        f32x4 xv = *(const f32x4*)(xr + k2 * 8);
                        f32x4 wv = *(const f32x4*)(wr + k2 * 8);
                        f32x4 xu = *(const f32x4*)(xr + k2 * 8 + 4);
                        f32x4 wu = *(const f32x4*)(wr + k2 * 8 + 4);
                        s0 += (double)xv[0] * wv[0] + (double)xv[1] * wv[1]
                            + (double)xv[2] * wv[2] + (double)xv[3] * wv[3];
                        s1 += (double)xu[0] * wu[0] + (double)xu[1] * wu[1]
                            + (double)xu[2] * wu[2] + (double)xu[3] * wu[3];
                    }
                    double zt = s0 + s1 + (double)bias[(size_t)tree * NNODES + nd];
                    zc[nd] = (zt <= 0.0) ? -1.f : 1.f;
                }
            }
            float mn2;
            leaf = traverse(zc, &mn2);
        }
        pk |= (unsigned)leaf << (8 * j);
    }
    if (tg < 12 || p == 0)
        *(unsigned int*)(idxb + (size_t)sg * NTREES + tg * 8 + p * 4) = pk;
}

// ---- K3: leaf gather (bf16 leaves) + forest mean (r1 verbatim) --------------
__global__ void leaf_gather(const unsigned char* __restrict__ idxb,
                            const bf16* __restrict__ lv16,
                            float* __restrict__ out) {
    const int wave = threadIdx.x >> 6;
    const int lane = threadIdx.x & 63;
    const int s = blockIdx.x * 4 + wave;
    unsigned int rw = 0;
    if (lane < 25) rw = *(const unsigned int*)(idxb + (size_t)s * NTREES + lane * 4);
    float acc = 0.f;
#pragma unroll 10
    for (int t = 0; t < NTREES; ++t) {
        unsigned int wrd = __shfl(rw, t >> 2);
        int li = (wrd >> ((t & 3) * 8)) & 255;
        acc += (float)lv16[((size_t)t * NLEAF + li) * NCLS + lane];
    }
    out[(size_t)s * NCLS + lane] = acc * 0.01f;
}

// ---------------------------------------------------------------------------
extern "C" void kernel_launch(void* const* d_in, const int* in_sizes, int n_in,
                              void* d_out, int out_size, void* d_ws, size_t ws_size,
                              hipStream_t stream) {
    const float* x  = (const float*)d_in[0];   // [8192,256]
    const float* nw = (const float*)d_in[1];   // [100,31,256]
    const float* nb = (const float*)d_in[2];   // [100,31]
    const float* lv = (const float*)d_in[3];   // [100,32,64]
    float* out = (float*)d_out;

    char* ws = (char*)d_ws;
    bf16* xh   = (bf16*)(ws + 0);                           // 4,194,304
    bf16* xl   = (bf16*)(ws + 4194304);                     // 4,194,304
    bf16* wimg = (bf16*)(ws + 8388608);                     // 1,703,936
    unsigned char* idxb = (unsigned char*)(ws + 10092544);  //   819,200
    bf16* lv16 = (bf16*)(ws + 10911744);                    //   409,600
    if (ws_size < (size_t)11321344) return;

    prep<<<2032, 256, 0, stream>>>(x, nw, lv, xh, xl, wimg, lv16);
    forest_all<<<dim3(13, 32), 512, 0, stream>>>(
        xh, xl, wimg, x, nw, nb, idxb);
    leaf_gather<<<NB / 4, 256, 0, stream>>>(idxb, lv16, out);
}

// Round 10
// 108.350 us; speedup vs baseline: 1.1812x; 1.0564x over previous
//
#include <hip/hip_runtime.h>

// ---------------------------------------------------------------------------
// RandomForest: 100 trees, depth 5, D=256, B=8192, C=64.
// FINAL (r10) = r1 verbatim, the best measured configuration (108.4us).
// Ten-round ledger: every structural deviation from this design regressed
// (in-kernel conversion +3, tg=4 +14, rolled K +13, stage-once +19, kernel
// split +13, in-lane fixup +6). Timed window ~= 87us harness poison fills
// (2x256MiB, untouchable) + ~21us of our kernels; residual headroom in
// forest_all (~4-5us via HK-grade pipelining) is below the +-4-5us fill-noise
// band of this harness.
//  * decision = sign(w.x + b); routing reads only node rows 0..15.
//  * prep: X -> split-bf16 (hi/lo) A-swizzled; W -> pre-swizzled LDS image
//    (13 groups x 8 trees, 4 zero dummy trees); leaves -> bf16.
//  * forest: 8 waves x M=32, N=128; double-buffered quarter-K B staging via
//    global_load_lds; 3-MFMA split (hi*hi + hi*lo + lo*hi, sigma_z ~ 6e-5);
//    register-select traversal; near-ties (TAU = 2e-3 ~ 33 sigma) queued for
//    the external fp64 fixup kernel (dense, off the hot path).
//  * leaf_gather: bf16 leaves (absmax 2^-9, accepted throughout).
// ---------------------------------------------------------------------------

typedef __bf16 bf16;
typedef __attribute__((ext_vector_type(8))) __bf16 bf16x8;
typedef __attribute__((ext_vector_type(4))) float f32x4;

#define NTREES 100
#define NB     8192
#define ND     256
#define NNODES 31
#define NLEAF  32
#define NCLS   64
#define TAU    2.0e-3f
#define QCAP   8192

static __device__ __forceinline__ void gload16(const void* g, void* l) {
    __builtin_amdgcn_global_load_lds(
        (const __attribute__((address_space(1))) void*)g,
        (__attribute__((address_space(3))) void*)l, 16, 0, 0);
}

// ---- K1: prep ---------------------------------------------------------------
// blocks 0..1023: X split (layout: i = g*4096 + dq*128 + m*8 + e).
// blocks 1024..1231: W image, 13 tg x [4 kq x (hi 16KB | lo 16KB)];
//   within: row*64 + (oct^(row&7))*8, oct = k-octet within quarter.
// blocks 1232..2031: leaves -> bf16.
__global__ void prep(const float* __restrict__ x, const float* __restrict__ wf,
                     const float* __restrict__ lv,
                     bf16* __restrict__ xh, bf16* __restrict__ xl,
                     bf16* __restrict__ wimg, bf16* __restrict__ lv16,
                     unsigned int* __restrict__ qcount) {
    if (blockIdx.x == 0 && threadIdx.x == 0) *qcount = 0;
    if (blockIdx.x < 1024) {
        int i = blockIdx.x * 256 + threadIdx.x;       // 0 .. 262143
        int m  = i & 15;
        int dq = (i >> 4) & 31;
        int g  = i >> 9;
        const float* src = x + (size_t)(g * 16 + m) * ND + dq * 8;
        bf16x8 h8, l8;
#pragma unroll
        for (int e = 0; e < 8; ++e) {
            float f = src[e];
            bf16 h = (bf16)f;
            h8[e] = h;
            l8[e] = (bf16)(f - (float)h);
        }
        *(bf16x8*)(xh + (size_t)i * 8) = h8;
        *(bf16x8*)(xl + (size_t)i * 8) = l8;
    } else if (blockIdx.x < 1232) {
        int i = (blockIdx.x - 1024) * 256 + threadIdx.x;  // 0..53247
        int oct_g = i & 31;          // global k-octet 0..31
        int row   = (i >> 5) & 127;  // B row 0..127
        int tg    = i >> 12;         // tree group 0..12
        int tree  = tg * 8 + (row >> 4), node = row & 15;
        bf16x8 h8, l8;
        if (tree < NTREES) {
            const float* src = wf + ((size_t)tree * NNODES + node) * ND + oct_g * 8;
#pragma unroll
            for (int e = 0; e < 8; ++e) {
                float f = src[e];
                bf16 h = (bf16)f;
                h8[e] = h;
                l8[e] = (bf16)(f - (float)h);
            }
        } else {
#pragma unroll
            for (int e = 0; e < 8; ++e) { h8[e] = (bf16)0.f; l8[e] = (bf16)0.f; }
        }
        int kq = oct_g >> 3, oct = oct_g & 7, cp = oct ^ (row & 7);
        size_t b = (size_t)tg * 65536 + (size_t)kq * 16384 + row * 64 + cp * 8;
        *(bf16x8*)(wimg + b)        = h8;   // hi
        *(bf16x8*)(wimg + b + 8192) = l8;   // lo
    } else {
        int i = (blockIdx.x - 1232) * 256 + threadIdx.x;  // 0..204799
        lv16[i] = (bf16)lv[i];
    }
}

// ---- K2: GEMM + traversal ----------------------------------------------------
// block: 256 samples x 8 trees (128 cols). 8 waves, each M=32, N=128.
__global__ __launch_bounds__(512, 4) void forest_all(
    const bf16* __restrict__ xh, const bf16* __restrict__ xl,
    const bf16* __restrict__ wimg,
    const float* __restrict__ bias,    // [100][31]
    unsigned char* __restrict__ idxb,  // [8192][100]
    unsigned int* __restrict__ qcount, unsigned int* __restrict__ queue)
{
    __shared__ char lds[65536];            // two 32KB B buffers; scr overlays after loop

    const int tid  = threadIdx.x;
    const int wave = tid >> 6;             // 0..7
    const int lane = tid & 63;
    const int m    = lane & 15;
    const int q    = lane >> 4;

    const int lin  = blockIdx.x + gridDim.x * blockIdx.y;   // 0..415
    const int xcd  = lin & 7;
    const int slot = lin >> 3;             // 0..51
    const int mg   = xcd * 4 + (slot / 13);
    const int tg   = slot % 13;            // tree-group of 8 (tg 12: 4 real)

    f32x4 acc[2][8];
#pragma unroll
    for (int mi = 0; mi < 2; ++mi)
#pragma unroll
        for (int ni = 0; ni < 8; ++ni)
            acc[mi][ni] = (f32x4){0.f, 0.f, 0.f, 0.f};

    size_t abase[2];
#pragma unroll
    for (int mi = 0; mi < 2; ++mi)
        abase[mi] = (size_t)(mg * 16 + wave * 2 + mi) * 4096 + lane * 8;

    const bf16* wsrc = wimg + (size_t)tg * 65536;

    // ---- stage kq=0 into buf0, then loop with 1-ahead async staging
#pragma unroll
    for (int j = 0; j < 4; ++j) {
        int idx = j * 512 + tid;           // 2048 16B chunks = 32KB
        gload16(wsrc + idx * 8, lds + idx * 16);
    }
    __syncthreads();

#pragma unroll
    for (int kq = 0; kq < 4; ++kq) {
        const char* bufc = lds + (kq & 1) * 32768;
        if (kq < 3) {                      // async-stage next quarter
            char* bufn = lds + ((kq + 1) & 1) * 32768;
#pragma unroll
            for (int j = 0; j < 4; ++j) {
                int idx = j * 512 + tid;
                gload16(wsrc + (size_t)(kq + 1) * 16384 + idx * 8, bufn + idx * 16);
            }
        }
#pragma unroll
        for (int kkq = 0; kkq < 2; ++kkq) {
            const int kk = kq * 2 + kkq;
            bf16x8 cah[2], cal[2];
#pragma unroll
            for (int mi = 0; mi < 2; ++mi) {
                cah[mi] = *(const bf16x8*)(xh + abase[mi] + kk * 512);
                cal[mi] = *(const bf16x8*)(xl + abase[mi] + kk * 512);
            }
#pragma unroll
            for (int ni = 0; ni < 8; ++ni) {
                const int n  = ni * 16 + m;
                const int cp = (kkq * 4 + q) ^ (m & 7);
                bf16x8 bh = *(const bf16x8*)((const bf16*)bufc + n * 64 + cp * 8);
                bf16x8 bl = *(const bf16x8*)((const bf16*)bufc + 8192 + n * 64 + cp * 8);
#pragma unroll
                for (int mi = 0; mi < 2; ++mi) {
                    acc[mi][ni] = __builtin_amdgcn_mfma_f32_16x16x32_bf16(cal[mi], bh, acc[mi][ni], 0, 0, 0);
                    acc[mi][ni] = __builtin_amdgcn_mfma_f32_16x16x32_bf16(cah[mi], bl, acc[mi][ni], 0, 0, 0);
                    acc[mi][ni] = __builtin_amdgcn_mfma_f32_16x16x32_bf16(cah[mi], bh, acc[mi][ni], 0, 0, 0);
                }
            }
        }
        __syncthreads();   // next buffer staged AND current fully consumed
    }

    // ---- epilogue: per-wave transpose via LDS, register-select traversal.
    // scr per wave: [32 rows][44 floats] (two 20-float ni slots + pad).
    // Lane halves: p = lane>>5 owns ni quad {p*4 .. p*4+3}; r = lane&31 = row.
    float biasv[8];
#pragma unroll
    for (int ni = 0; ni < 8; ++ni) {
        int tree = tg * 8 + ni;
        biasv[ni] = (tree < NTREES) ? bias[(size_t)tree * NNODES + m] : 0.f;
    }

    float* ws_ = (float*)lds + wave * 1408;        // 32*44 floats per wave
    const int p = lane >> 5;
    const int r = lane & 31;
    const int sg = mg * 256 + wave * 32 + r;
    unsigned int pk = 0;
#pragma unroll
    for (int j = 0; j < 4; ++j) {
        // write two ni slots: slot0 = ni j (bias j), slot1 = ni j+4
#pragma unroll
        for (int mi = 0; mi < 2; ++mi)
#pragma unroll
            for (int rr = 0; rr < 4; ++rr) {
                int row = mi * 16 + q * 4 + rr;
                ws_[row * 44 + m]      = acc[mi][j][rr]     + biasv[j];
                ws_[row * 44 + 20 + m] = acc[mi][j + 4][rr] + biasv[j + 4];
            }
        f32x4 z0 = *(f32x4*)&ws_[r * 44 + p * 20];
        f32x4 z1 = *(f32x4*)&ws_[r * 44 + p * 20 + 4];
        f32x4 z2 = *(f32x4*)&ws_[r * 44 + p * 20 + 8];
        f32x4 z3 = *(f32x4*)&ws_[r * 44 + p * 20 + 12];
        float z[16] = {z0[0], z0[1], z0[2], z0[3], z1[0], z1[1], z1[2], z1[3],
                       z2[0], z2[1], z2[2], z2[3], z3[0], z3[1], z3[2], z3[3]};
        float a0 = z[0];
        bool d0 = a0 <= 0.f;
        float a1 = d0 ? z[1] : z[0];
        bool d1 = a1 <= 0.f;
        float a2 = d0 ? (d1 ? z[3] : z[2]) : (d1 ? z[1] : z[0]);
        bool d2 = a2 <= 0.f;
        float m0 = d2 ? z[1] : z[0], m1 = d2 ? z[3] : z[2];
        float m2 = d2 ? z[5] : z[4], m3 = d2 ? z[7] : z[6];
        float p0 = d1 ? m1 : m0, p1 = d1 ? m3 : m2;
        float a3 = d0 ? p1 : p0;
        bool d3 = a3 <= 0.f;
        float n0 = d3 ? z[1] : z[0],  n1 = d3 ? z[3] : z[2];
        float n2 = d3 ? z[5] : z[4],  n3 = d3 ? z[7] : z[6];
        float n4 = d3 ? z[9] : z[8],  n5 = d3 ? z[11] : z[10];
        float n6 = d3 ? z[13] : z[12], n7 = d3 ? z[15] : z[14];
        float q0 = d2 ? n1 : n0, q1 = d2 ? n3 : n2;
        float q2 = d2 ? n5 : n4, q3 = d2 ? n7 : n6;
        float r0 = d1 ? q1 : q0, r1 = d1 ? q3 : q2;
        float a4 = d0 ? r1 : r0;
        bool d4 = a4 <= 0.f;
        int leaf = ((int)d0 << 4) | ((int)d1 << 3) | ((int)d2 << 2)
                 | ((int)d3 << 1) | (int)d4;
        pk |= (unsigned)leaf << (8 * j);
        float mn = fminf(fminf(fminf(fabsf(a0), fabsf(a1)),
                               fminf(fabsf(a2), fabsf(a3))), fabsf(a4));
        const int tree = tg * 8 + (j + p * 4);
        if (tree < NTREES && mn < TAU) {   // dummy trees (z==0) must not enqueue
            unsigned int pos = atomicAdd(qcount, 1u);
            if (pos < QCAP)
                queue[pos] = ((unsigned)tree << 13) | (unsigned)sg;
        }
    }
    if (tg < 12 || p == 0)
        *(unsigned int*)(idxb + (size_t)sg * NTREES + tg * 8 + p * 4) = pk;
}

// ---- K3: exact fp64 re-traversal of queued near-ties ------------------------
__global__ void fixup_kernel(const float* __restrict__ x, const float* __restrict__ wf,
                             const float* __restrict__ bias,
                             const unsigned int* __restrict__ qcount,
                             const unsigned int* __restrict__ queue,
                             unsigned char* __restrict__ idxb) {
    const int wid  = (blockIdx.x * 256 + threadIdx.x) >> 6;   // global wave id
    const int lane = threadIdx.x & 63;
    unsigned int n = *qcount;
    if (n > QCAP) n = QCAP;
    for (unsigned int it = wid; it < n; it += 256) {
        unsigned int e = queue[it];
        int t = e >> 13, s = e & 8191;
        const float* xr = x + (size_t)s * ND;
        float4 xv = *(const float4*)(xr + lane * 4);
        int node = 0;
        for (int lvl = 0; lvl < 5; ++lvl) {
            const float* wr = wf + ((size_t)t * NNODES + node) * ND;
            float4 wv = *(const float4*)(wr + lane * 4);
            double zz = (double)xv.x * wv.x + (double)xv.y * wv.y
                      + (double)xv.z * wv.z + (double)xv.w * wv.w;
#pragma unroll
            for (int o = 32; o > 0; o >>= 1) zz += __shfl_xor(zz, o);
            zz += (double)bias[t * NNODES + node];
            node = 2 * node + (zz <= 0.0 ? 1 : 0);
        }
        if (lane == 0) idxb[(size_t)s * NTREES + t] = (unsigned char)node;
    }
}

// ---- K4: leaf gather (bf16 leaves) + forest mean ----------------------------
__global__ void leaf_gather(const unsigned char* __restrict__ idxb,
                            const bf16* __restrict__ lv16,
                            float* __restrict__ out) {
    const int wave = threadIdx.x >> 6;
    const int lane = threadIdx.x & 63;
    const int s = blockIdx.x * 4 + wave;
    unsigned int rw = 0;
    if (lane < 25) rw = *(const unsigned int*)(idxb + (size_t)s * NTREES + lane * 4);
    float acc = 0.f;
#pragma unroll 10
    for (int t = 0; t < NTREES; ++t) {
        unsigned int wrd = __shfl(rw, t >> 2);
        int li = (wrd >> ((t & 3) * 8)) & 255;
        acc += (float)lv16[((size_t)t * NLEAF + li) * NCLS + lane];
    }
    out[(size_t)s * NCLS + lane] = acc * 0.01f;
}

// ---------------------------------------------------------------------------
extern "C" void kernel_launch(void* const* d_in, const int* in_sizes, int n_in,
                              void* d_out, int out_size, void* d_ws, size_t ws_size,
                              hipStream_t stream) {
    const float* x  = (const float*)d_in[0];   // [8192,256]
    const float* nw = (const float*)d_in[1];   // [100,31,256]
    const float* nb = (const float*)d_in[2];   // [100,31]
    const float* lv = (const float*)d_in[3];   // [100,32,64]
    float* out = (float*)d_out;

    char* ws = (char*)d_ws;
    bf16* xh   = (bf16*)(ws + 0);                           // 4,194,304
    bf16* xl   = (bf16*)(ws + 4194304);                     // 4,194,304
    bf16* wimg = (bf16*)(ws + 8388608);                     // 1,703,936
    unsigned char* idxb = (unsigned char*)(ws + 10092544);  //   819,200
    bf16* lv16 = (bf16*)(ws + 10911744);                    //   409,600
    unsigned int* qcount = (unsigned int*)(ws + 11321344);  //        16
    unsigned int* queue  = (unsigned int*)(ws + 11321360);  //    32,768
    if (ws_size < (size_t)11354128) return;

    prep<<<2032, 256, 0, stream>>>(x, nw, lv, xh, xl, wimg, lv16, qcount);
    forest_all<<<dim3(13, 32), 512, 0, stream>>>(
        xh, xl, wimg, nb, idxb, qcount, queue);
    fixup_kernel<<<64, 256, 0, stream>>>(x, nw, nb, qcount, queue, idxb);
    leaf_gather<<<NB / 4, 256, 0, stream>>>(idxb, lv16, out);
}